// Round 8
// baseline (209.234 us; speedup 1.0000x reference)
//
#include <hip/hip_runtime.h>
#include <hip/hip_bf16.h>

// Problem constants (from reference)
#define D_IN    256
#define D_OUT   64
#define NNODES  50000
#define NEDGES  1250000

#define BUCK_SHIFT 8                       // 256 nodes per bucket
#define BUCK_NODES 256
#define NBUCK      196                     // ceil(50000/256)
#define CPAD       16                      // pad counters to 64B lines
#define EPB        4096                    // edges per binning block
#define NB_EDGE    ((NEDGES + EPB - 1) / EPB)   // 306

typedef float f32x4 __attribute__((ext_vector_type(4)));
typedef short s16x8 __attribute__((ext_vector_type(8)));   // 8 bf16 (4 VGPRs)

// fp32 -> bf16 bits, round-to-nearest-even
static __device__ __forceinline__ unsigned short f2bf(float f) {
    union { float f; unsigned u; } v; v.f = f;
    unsigned r = v.u + 0x7FFFu + ((v.u >> 16) & 1u);
    return (unsigned short)(r >> 16);
}
static __device__ __forceinline__ float bf2f(unsigned short b) {
    union { unsigned u; float f; } v; v.u = ((unsigned)b) << 16;
    return v.f;
}
// unpack packed bf16 pair (low half / high half of a uint)
static __device__ __forceinline__ float blo(unsigned u) {
    union { unsigned u; float f; } v; v.u = u << 16; return v.f;
}
static __device__ __forceinline__ float bhi(unsigned u) {
    union { unsigned u; float f; } v; v.u = u & 0xFFFF0000u; return v.f;
}

// ---------------------------------------------------------------------------
// Kernel 0 (fallback path only): W fp32 -> bf16
// ---------------------------------------------------------------------------
__global__ __launch_bounds__(256) void convert_w(
    const float* __restrict__ W, unsigned short* __restrict__ Wb)
{
    int i = blockIdx.x * 256 + threadIdx.x;
    if (i < D_OUT * D_IN) Wb[i] = f2bf(W[i]);
}

// ---------------------------------------------------------------------------
// Kernel 1: coarse histogram over 196 buckets (LDS-private) + W conversion
// fused as the extra last block (independent work, runs concurrently).
// ---------------------------------------------------------------------------
__global__ __launch_bounds__(256) void coarse_hist(
    const int* __restrict__ dst, int* __restrict__ bcount,
    const float* __restrict__ W, unsigned short* __restrict__ Wb)
{
    if (blockIdx.x == NB_EDGE) {   // fused W -> bf16 (16K elems)
        for (int i = threadIdx.x; i < D_OUT * D_IN; i += 256)
            Wb[i] = f2bf(W[i]);
        return;
    }
    __shared__ int lh[NBUCK];
    int t = threadIdx.x;
    for (int i = t; i < NBUCK; i += 256) lh[i] = 0;
    __syncthreads();
    int base = blockIdx.x * EPB;
    int end  = min(base + EPB, NEDGES);
    for (int e = base + t; e < end; e += 256)
        atomicAdd(&lh[dst[e] >> BUCK_SHIFT], 1);
    __syncthreads();
    if (t < NBUCK) {
        int c = lh[t];
        if (c) atomicAdd(&bcount[t * CPAD], c);
    }
}

// ---------------------------------------------------------------------------
// Kernel 2: h[N,64] = x[N,256] @ W[64,256]^T  via bf16 MFMA (fp32 accum).
// W staged in LDS pre-swizzled into MFMA B-fragment order (conflict-free
// lane-contiguous ds_read_b128, zero per-iteration B conversion).
// ---------------------------------------------------------------------------
__global__ __launch_bounds__(256) void gemm_h_mfma(
    const float* __restrict__ x, const unsigned short* __restrict__ Wb,
    unsigned short* __restrict__ h, int N)
{
    __shared__ uint4 sW[2048];   // 32 KB: 4 c * 8 kb * 64 lanes

    const int t    = threadIdx.x;
    const int lane = t & 63;
    const int wave = t >> 6;
    const int m    = lane & 15;
    const int q    = lane >> 4;

    #pragma unroll
    for (int i = 0; i < 8; ++i) {
        int slot = t + i * 256;
        int ln   = slot & 63;
        int kb   = (slot >> 6) & 7;
        int c    = slot >> 9;
        int lm = ln & 15, lq = ln >> 4;
        sW[slot] = ((const uint4*)Wb)[(c * 16 + lm) * 32 + kb * 4 + lq];
    }
    __syncthreads();

    const int rowA = blockIdx.x * 64 + wave * 16 + m;
    const int rowc = (rowA < N) ? rowA : (N - 1);
    const float* xr = x + (long long)rowc * D_IN + q * 8;

    f32x4 acc[4] = {};

    #pragma unroll
    for (int kb = 0; kb < 8; ++kb) {
        float4 a0 = *(const float4*)(xr + kb * 32);
        float4 a1 = *(const float4*)(xr + kb * 32 + 4);
        s16x8 af;
        af[0] = (short)f2bf(a0.x); af[1] = (short)f2bf(a0.y);
        af[2] = (short)f2bf(a0.z); af[3] = (short)f2bf(a0.w);
        af[4] = (short)f2bf(a1.x); af[5] = (short)f2bf(a1.y);
        af[6] = (short)f2bf(a1.z); af[7] = (short)f2bf(a1.w);

        #pragma unroll
        for (int c = 0; c < 4; ++c) {
            s16x8 bf = *(const s16x8*)&sW[(c * 8 + kb) * 64 + lane];
            acc[c] = __builtin_amdgcn_mfma_f32_16x16x32_bf16(af, bf, acc[c], 0, 0, 0);
        }
    }

    #pragma unroll
    for (int c = 0; c < 4; ++c) {
        #pragma unroll
        for (int r = 0; r < 4; ++r) {
            int gr = blockIdx.x * 64 + wave * 16 + q * 4 + r;
            if (gr < N)
                h[(long long)gr * D_OUT + c * 16 + m] = f2bf(acc[c][r]);
        }
    }
}

// ---------------------------------------------------------------------------
// Kernel 3: bin edges into bucket-grouped regions. Bucket bases recomputed
// per block by an inline LDS scan of bcount (196 L2-hot reads) -> the
// separate bucket_scan dispatch is gone. bcursor holds RELATIVE offsets
// (zero-initialized by the same memset as bcount).
// rec = [wt:32 | dst_local:8 (bits16..23) | src:16 (lo)]
// ---------------------------------------------------------------------------
__global__ __launch_bounds__(256) void bin_edges(
    const int* __restrict__ src, const int* __restrict__ dst,
    const float* __restrict__ wt, const int* __restrict__ bcount,
    int* __restrict__ bcursor, unsigned long long* __restrict__ binned)
{
    __shared__ int s[256];
    __shared__ int bstartL[NBUCK];
    __shared__ int lcnt[NBUCK];
    __shared__ int lbase[NBUCK];
    int t = threadIdx.x;

    // inline exclusive scan of bucket counts
    int v = (t < NBUCK) ? bcount[t * CPAD] : 0;
    s[t] = v;
    for (int i = t; i < NBUCK; i += 256) lcnt[i] = 0;
    __syncthreads();
    #pragma unroll
    for (int off = 1; off < 256; off <<= 1) {
        int u = (t >= off) ? s[t - off] : 0;
        __syncthreads();
        s[t] += u;
        __syncthreads();
    }
    if (t < NBUCK) bstartL[t] = s[t] - v;
    __syncthreads();

    int base = blockIdx.x * EPB;
    int end  = min(base + EPB, NEDGES);

    for (int e = base + t; e < end; e += 256)
        atomicAdd(&lcnt[dst[e] >> BUCK_SHIFT], 1);
    __syncthreads();

    if (t < NBUCK) {
        int c = lcnt[t];
        lbase[t] = c ? (bstartL[t] + atomicAdd(&bcursor[t * CPAD], c)) : 0;
        lcnt[t]  = 0;   // reuse as local rank counter
    }
    __syncthreads();

    for (int e = base + t; e < end; e += 256) {
        int d = dst[e];
        int b = d >> BUCK_SHIFT;
        int r = atomicAdd(&lcnt[b], 1);
        unsigned lo = (unsigned)src[e] | ((unsigned)(d & (BUCK_NODES - 1)) << 16);
        unsigned long long rec = (unsigned long long)lo
                               | ((unsigned long long)__float_as_uint(wt[e]) << 32);
        binned[lbase[b] + r] = rec;
    }
}

// ---------------------------------------------------------------------------
// Kernel 4: per-bucket counting sort to per-node CSR. One block per bucket;
// bucket range recomputed by inline scan of bcount.
// ---------------------------------------------------------------------------
__global__ __launch_bounds__(256) void sort_buckets(
    const unsigned long long* __restrict__ binned, const int* __restrict__ bcount,
    unsigned long long* __restrict__ csr,
    int* __restrict__ starts, int* __restrict__ counts)
{
    __shared__ int s[256];
    __shared__ int lcnt[BUCK_NODES];
    __shared__ int lcur[BUCK_NODES];
    __shared__ int sh_s0, sh_e0;
    int t = threadIdx.x;
    int b = blockIdx.x;

    // inline scan of bucket counts -> this bucket's [s0, e0)
    int v = (t < NBUCK) ? bcount[t * CPAD] : 0;
    s[t] = v;
    lcnt[t] = 0;
    __syncthreads();
    #pragma unroll
    for (int off = 1; off < 256; off <<= 1) {
        int u = (t >= off) ? s[t - off] : 0;
        __syncthreads();
        s[t] += u;
        __syncthreads();
    }
    if (t == b) { sh_e0 = s[t]; sh_s0 = s[t] - v; }
    __syncthreads();
    int s0 = sh_s0, e0 = sh_e0;
    int node0 = b << BUCK_SHIFT;
    int nn = min(BUCK_NODES, NNODES - node0);

    for (int k = s0 + t; k < e0; k += 256)
        atomicAdd(&lcnt[(int)((binned[k] >> 16) & 0xFF)], 1);
    __syncthreads();

    int v2 = lcnt[t];
    s[t] = v2; __syncthreads();
    #pragma unroll
    for (int off = 1; off < 256; off <<= 1) {
        int u = (t >= off) ? s[t - off] : 0;
        __syncthreads();
        s[t] += u;
        __syncthreads();
    }
    int excl = s[t] - v2;
    lcur[t] = s0 + excl;
    if (t < nn) {
        starts[node0 + t] = s0 + excl;
        counts[node0 + t] = v2;
    }
    __syncthreads();

    for (int k = s0 + t; k < e0; k += 256) {
        unsigned long long r = binned[k];
        int dloc = (int)((r >> 16) & 0xFF);
        int pos  = atomicAdd(&lcur[dloc], 1);
        csr[pos] = r;
    }
}

// ---------------------------------------------------------------------------
// Kernel 5: aggregation v3. One wave per node; 4 groups of 16 lanes, each
// group = one edge, each lane = 4 columns (uint2 = 8B gather). One VMEM
// instruction serves 4 edges (512B) vs 1 edge (128B) before. x2 unroll ->
// 8 edges in flight. Butterfly shfl_xor {16,32} merges groups; lanes 0-15
// write float4 + bias.
// ---------------------------------------------------------------------------
__global__ __launch_bounds__(256) void agg_nodes(
    const int2* __restrict__ recs, const int* __restrict__ starts,
    const int* __restrict__ counts, const unsigned short* __restrict__ h,
    const float* __restrict__ bias, float* __restrict__ out)
{
    int wid  = (blockIdx.x * 256 + threadIdx.x) >> 6;
    int node = __builtin_amdgcn_readfirstlane(wid);
    if (node >= NNODES) return;
    int lane = threadIdx.x & 63;
    int g    = lane >> 4;        // edge group 0..3
    int c4   = lane & 15;        // column quad: cols 4*c4 .. 4*c4+3

    int s0 = starts[node];
    int e0 = s0 + counts[node];

    float a0 = 0.f, a1 = 0.f, a2 = 0.f, a3 = 0.f;

    for (int i = s0; i < e0; i += 8) {
        int ia = i + g;
        int ib = i + 4 + g;
        int ca = min(ia, e0 - 1);
        int cb = min(ib, e0 - 1);
        int2 ra = recs[ca];
        int2 rb = recs[cb];
        float wa = (ia < e0) ? __int_as_float(ra.y) : 0.0f;
        float wb = (ib < e0) ? __int_as_float(rb.y) : 0.0f;
        uint2 ua = *(const uint2*)&h[(ra.x & 0xFFFF) * D_OUT + c4 * 4];
        uint2 ub = *(const uint2*)&h[(rb.x & 0xFFFF) * D_OUT + c4 * 4];
        a0 += wa * blo(ua.x); a1 += wa * bhi(ua.x);
        a2 += wa * blo(ua.y); a3 += wa * bhi(ua.y);
        a0 += wb * blo(ub.x); a1 += wb * bhi(ub.x);
        a2 += wb * blo(ub.y); a3 += wb * bhi(ub.y);
    }

    // merge the 4 edge-groups (lane bits 4 and 5)
    a0 += __shfl_xor(a0, 16); a1 += __shfl_xor(a1, 16);
    a2 += __shfl_xor(a2, 16); a3 += __shfl_xor(a3, 16);
    a0 += __shfl_xor(a0, 32); a1 += __shfl_xor(a1, 32);
    a2 += __shfl_xor(a2, 32); a3 += __shfl_xor(a3, 32);

    if (g == 0) {
        float4 b4 = *(const float4*)&bias[c4 * 4];
        float4 o  = make_float4(a0 + b4.x, a1 + b4.y, a2 + b4.z, a3 + b4.w);
        *(float4*)&out[(long long)node * D_OUT + c4 * 4] = o;
    }
}

// ---------------------------------------------------------------------------
// Fallback path (ws too small): bias init + per-edge atomics
// ---------------------------------------------------------------------------
__global__ __launch_bounds__(256) void init_bias(
    float* __restrict__ out, const float* __restrict__ bias, int total)
{
    int i = blockIdx.x * blockDim.x + threadIdx.x;
    if (i < total) out[i] = bias[i & (D_OUT - 1)];
}

__global__ __launch_bounds__(256) void scatter_edges(
    const int* __restrict__ src, const int* __restrict__ dst,
    const float* __restrict__ wt, const unsigned short* __restrict__ h,
    float* __restrict__ out)
{
    long long gid = (long long)blockIdx.x * blockDim.x + threadIdx.x;
    int e    = (int)(gid >> 6);
    int lane = threadIdx.x & 63;
    if (e < NEDGES) {
        int   s = src[e];
        int   d = dst[e];
        float w = wt[e];
        float v = w * bf2f(h[(long long)s * D_OUT + lane]);
        atomicAdd(&out[(long long)d * D_OUT + lane], v);
    }
}

// ---------------------------------------------------------------------------
// Launch
// ---------------------------------------------------------------------------
extern "C" void kernel_launch(void* const* d_in, const int* in_sizes, int n_in,
                              void* d_out, int out_size, void* d_ws, size_t ws_size,
                              hipStream_t stream)
{
    const float* W     = (const float*)d_in[0];   // [64, 256]
    const float* bias  = (const float*)d_in[1];   // [64]
    const int*   edges = (const int*)  d_in[2];   // [2, E]
    const float* wt    = (const float*)d_in[3];   // [E]
    const float* x     = (const float*)d_in[4];   // [N, 256]
    float*       out   = (float*)d_out;           // [N, 64]

    const int* src = edges;
    const int* dst = edges + NEDGES;

    // workspace carve-up (bytes)
    char* ws = (char*)d_ws;
    const size_t OFF_H      = 0;                   // 6,400,000   (bf16 h)
    const size_t OFF_WB     = 6400000;             // 32,768     (bf16 W)
    const size_t OFF_RECS   = 6432768;             // 10,000,000 (CSR recs)
    const size_t OFF_STARTS = 16432768;            // 200,000
    const size_t OFF_COUNTS = 16632768;            // 200,000
    const size_t OFF_BCOUNT = 16832768;            // 12,544
    const size_t OFF_BCUR   = 16845312;            // 12,544 (contiguous after bcount)
    const size_t REQUIRED   = 16857856;

    unsigned short* h  = (unsigned short*)(ws + OFF_H);
    unsigned short* Wb = (unsigned short*)(ws + OFF_WB);

    if (ws_size >= REQUIRED) {
        unsigned long long* csr     = (unsigned long long*)(ws + OFF_RECS);
        int*                starts  = (int*)(ws + OFF_STARTS);
        int*                counts  = (int*)(ws + OFF_COUNTS);
        int*                bcount  = (int*)(ws + OFF_BCOUNT);
        int*                bcursor = (int*)(ws + OFF_BCUR);

        // d_out doubles as scratch for bucket-binned recs (10 MB <= 12.8 MB);
        // agg_nodes fully overwrites it afterwards.
        unsigned long long* binned = (unsigned long long*)d_out;

        // one memset covers bcount + bcursor (contiguous)
        hipMemsetAsync(bcount, 0, 2 * NBUCK * CPAD * sizeof(int), stream);

        coarse_hist<<<NB_EDGE + 1, 256, 0, stream>>>(dst, bcount, W, Wb);
        gemm_h_mfma<<<(NNODES + 63) / 64, 256, 0, stream>>>(x, Wb, h, NNODES);
        bin_edges<<<NB_EDGE, 256, 0, stream>>>(src, dst, wt, bcount, bcursor, binned);
        sort_buckets<<<NBUCK, 256, 0, stream>>>(binned, bcount, csr, starts, counts);

        int nb = (NNODES * 64 + 255) / 256;  // 12500 blocks, 4 nodes/block
        agg_nodes<<<nb, 256, 0, stream>>>((const int2*)csr, starts, counts, h, bias, out);
    } else {
        convert_w<<<(D_OUT * D_IN + 255) / 256, 256, 0, stream>>>(W, Wb);
        gemm_h_mfma<<<(NNODES + 63) / 64, 256, 0, stream>>>(x, Wb, h, NNODES);
        int total = NNODES * D_OUT;
        init_bias<<<(total + 255) / 256, 256, 0, stream>>>(out, bias, total);
        long long threads = (long long)NEDGES * 64;
        int blocks = (int)((threads + 255) / 256);
        scatter_edges<<<blocks, 256, 0, stream>>>(src, dst, wt, h, out);
    }
}

// Round 10
// 207.284 us; speedup vs baseline: 1.0094x; 1.0094x over previous
//
#include <hip/hip_runtime.h>
#include <hip/hip_bf16.h>

// Problem constants (from reference)
#define D_IN    256
#define D_OUT   64
#define NNODES  50000
#define NEDGES  1250000

#define BUCK_SHIFT 8                       // 256 nodes per bucket
#define BUCK_NODES 256
#define NBUCK      196                     // ceil(50000/256)
#define CPAD       16                      // pad counters to 64B lines
#define EPB        4096                    // edges per binning block
#define NB_EDGE    ((NEDGES + EPB - 1) / EPB)   // 306

typedef float f32x4 __attribute__((ext_vector_type(4)));
typedef short s16x8 __attribute__((ext_vector_type(8)));   // 8 bf16 (4 VGPRs)

// fp32 -> bf16 bits, round-to-nearest-even
static __device__ __forceinline__ unsigned short f2bf(float f) {
    union { float f; unsigned u; } v; v.f = f;
    unsigned r = v.u + 0x7FFFu + ((v.u >> 16) & 1u);
    return (unsigned short)(r >> 16);
}
static __device__ __forceinline__ float bf2f(unsigned short b) {
    union { unsigned u; float f; } v; v.u = ((unsigned)b) << 16;
    return v.f;
}

// ---------------------------------------------------------------------------
// Kernel 0: one-time W fp32 -> bf16 (64x256 = 16K elements)
// ---------------------------------------------------------------------------
__global__ __launch_bounds__(256) void convert_w(
    const float* __restrict__ W, unsigned short* __restrict__ Wb)
{
    int i = blockIdx.x * 256 + threadIdx.x;
    if (i < D_OUT * D_IN) Wb[i] = f2bf(W[i]);
}

// ---------------------------------------------------------------------------
// Kernel 1: h[N,64] = x[N,256] @ W[64,256]^T  via bf16 MFMA (fp32 accum).
// W staged in LDS pre-swizzled into MFMA B-fragment order:
//   slot(c,kb,lane) = (c*8+kb)*64 + lane  (uint4 = 8 bf16 per slot)
// -> inner-loop ds_read_b128 is lane-contiguous (conflict-free), and NO
// per-iteration B conversion. Per kb: 2 global dwordx4 (x) + 8 f2bf +
// 4 ds_read_b128 + 4 MFMA.
// ---------------------------------------------------------------------------
__global__ __launch_bounds__(256) void gemm_h_mfma(
    const float* __restrict__ x, const unsigned short* __restrict__ Wb,
    unsigned short* __restrict__ h, int N)
{
    __shared__ uint4 sW[2048];   // 32 KB: 4 c * 8 kb * 64 lanes

    const int t    = threadIdx.x;
    const int lane = t & 63;
    const int wave = t >> 6;
    const int m    = lane & 15;
    const int q    = lane >> 4;

    // stage W fragments (gather from L2-resident 32 KB, store linear)
    #pragma unroll
    for (int i = 0; i < 8; ++i) {
        int slot = t + i * 256;
        int ln   = slot & 63;
        int kb   = (slot >> 6) & 7;
        int c    = slot >> 9;
        int lm = ln & 15, lq = ln >> 4;
        sW[slot] = ((const uint4*)Wb)[(c * 16 + lm) * 32 + kb * 4 + lq];
    }
    __syncthreads();

    const int rowA = blockIdx.x * 64 + wave * 16 + m;
    const int rowc = (rowA < N) ? rowA : (N - 1);
    const float* xr = x + (long long)rowc * D_IN + q * 8;

    f32x4 acc[4] = {};

    #pragma unroll
    for (int kb = 0; kb < 8; ++kb) {
        float4 a0 = *(const float4*)(xr + kb * 32);
        float4 a1 = *(const float4*)(xr + kb * 32 + 4);
        s16x8 af;
        af[0] = (short)f2bf(a0.x); af[1] = (short)f2bf(a0.y);
        af[2] = (short)f2bf(a0.z); af[3] = (short)f2bf(a0.w);
        af[4] = (short)f2bf(a1.x); af[5] = (short)f2bf(a1.y);
        af[6] = (short)f2bf(a1.z); af[7] = (short)f2bf(a1.w);

        #pragma unroll
        for (int c = 0; c < 4; ++c) {
            s16x8 bf = *(const s16x8*)&sW[(c * 8 + kb) * 64 + lane];
            acc[c] = __builtin_amdgcn_mfma_f32_16x16x32_bf16(af, bf, acc[c], 0, 0, 0);
        }
    }

    // C/D: col = c*16 + m, row = blk*64 + wave*16 + q*4 + r
    #pragma unroll
    for (int c = 0; c < 4; ++c) {
        #pragma unroll
        for (int r = 0; r < 4; ++r) {
            int gr = blockIdx.x * 64 + wave * 16 + q * 4 + r;
            if (gr < N)
                h[(long long)gr * D_OUT + c * 16 + m] = f2bf(acc[c][r]);
        }
    }
}

// ---------------------------------------------------------------------------
// Kernel 2: coarse histogram over 196 buckets (LDS-private, one padded
// global atomic per block-bucket).
// ---------------------------------------------------------------------------
__global__ __launch_bounds__(256) void coarse_hist(
    const int* __restrict__ dst, int* __restrict__ bcount)
{
    __shared__ int lh[NBUCK];
    int t = threadIdx.x;
    for (int i = t; i < NBUCK; i += 256) lh[i] = 0;
    __syncthreads();
    int base = blockIdx.x * EPB;
    int end  = min(base + EPB, NEDGES);
    for (int e = base + t; e < end; e += 256)
        atomicAdd(&lh[dst[e] >> BUCK_SHIFT], 1);
    __syncthreads();
    if (t < NBUCK) {
        int c = lh[t];
        if (c) atomicAdd(&bcount[t * CPAD], c);
    }
}

// ---------------------------------------------------------------------------
// Kernel 3: single-block scan of bucket counts -> bstart[NBUCK+1] + cursors.
// ---------------------------------------------------------------------------
__global__ __launch_bounds__(256) void bucket_scan(
    const int* __restrict__ bcount, int* __restrict__ bstart,
    int* __restrict__ bcursor)
{
    int t = threadIdx.x;
    int v = (t < NBUCK) ? bcount[t * CPAD] : 0;
    __shared__ int s[256];
    s[t] = v; __syncthreads();
    #pragma unroll
    for (int off = 1; off < 256; off <<= 1) {
        int u = (t >= off) ? s[t - off] : 0;
        __syncthreads();
        s[t] += u;
        __syncthreads();
    }
    if (t < NBUCK) {
        int st = s[t] - v;
        bstart[t] = st;
        bcursor[t * CPAD] = st;
    }
    if (t == 0) bstart[NBUCK] = NEDGES;
}

// ---------------------------------------------------------------------------
// Kernel 4: bin edges into bucket-grouped regions (runs of ~21 recs/bucket
// per block -> write lines mostly single-owner). Output = d_out scratch.
// rec = [wt:32 | dst_local:8 (bits16..23) | src:16 (lo)]
// ---------------------------------------------------------------------------
__global__ __launch_bounds__(256) void bin_edges(
    const int* __restrict__ src, const int* __restrict__ dst,
    const float* __restrict__ wt, int* __restrict__ bcursor,
    unsigned long long* __restrict__ binned)
{
    __shared__ int lcnt[NBUCK];
    __shared__ int lbase[NBUCK];
    int t = threadIdx.x;
    for (int i = t; i < NBUCK; i += 256) lcnt[i] = 0;
    __syncthreads();

    int base = blockIdx.x * EPB;
    int end  = min(base + EPB, NEDGES);

    for (int e = base + t; e < end; e += 256)
        atomicAdd(&lcnt[dst[e] >> BUCK_SHIFT], 1);
    __syncthreads();

    if (t < NBUCK) {
        int c = lcnt[t];
        lbase[t] = c ? atomicAdd(&bcursor[t * CPAD], c) : 0;
        lcnt[t]  = 0;   // reuse as local rank counter
    }
    __syncthreads();

    for (int e = base + t; e < end; e += 256) {
        int d = dst[e];
        int b = d >> BUCK_SHIFT;
        int r = atomicAdd(&lcnt[b], 1);
        unsigned lo = (unsigned)src[e] | ((unsigned)(d & (BUCK_NODES - 1)) << 16);
        unsigned long long rec = (unsigned long long)lo
                               | ((unsigned long long)__float_as_uint(wt[e]) << 32);
        binned[lbase[b] + r] = rec;
    }
}

// ---------------------------------------------------------------------------
// Kernel 5: per-bucket counting sort to per-node CSR. One block per bucket;
// streaming: count 256 local nodes in LDS, scan, write starts/counts,
// scatter recs from binned (d_out) into csr (ws).
// ---------------------------------------------------------------------------
__global__ __launch_bounds__(256) void sort_buckets(
    const unsigned long long* __restrict__ binned, const int* __restrict__ bstart,
    unsigned long long* __restrict__ csr,
    int* __restrict__ starts, int* __restrict__ counts)
{
    __shared__ int lcnt[BUCK_NODES];
    __shared__ int lcur[BUCK_NODES];
    __shared__ int s[256];
    int t = threadIdx.x;
    int b = blockIdx.x;
    int s0 = bstart[b];
    int e0 = bstart[b + 1];
    int node0 = b << BUCK_SHIFT;
    int nn = min(BUCK_NODES, NNODES - node0);

    lcnt[t] = 0;
    __syncthreads();

    for (int k = s0 + t; k < e0; k += 256)
        atomicAdd(&lcnt[(int)((binned[k] >> 16) & 0xFF)], 1);
    __syncthreads();

    int v = lcnt[t];
    s[t] = v; __syncthreads();
    #pragma unroll
    for (int off = 1; off < 256; off <<= 1) {
        int u = (t >= off) ? s[t - off] : 0;
        __syncthreads();
        s[t] += u;
        __syncthreads();
    }
    int excl = s[t] - v;
    lcur[t] = s0 + excl;          // absolute cursor within bucket region
    if (t < nn) {
        starts[node0 + t] = s0 + excl;
        counts[node0 + t] = v;
    }
    __syncthreads();

    for (int k = s0 + t; k < e0; k += 256) {
        unsigned long long r = binned[k];
        int dloc = (int)((r >> 16) & 0xFF);
        int pos  = atomicAdd(&lcur[dloc], 1);
        csr[pos] = r;
    }
}

// ---------------------------------------------------------------------------
// Kernel 6: aggregation. One wave per node, lane = output column, node in
// SGPR via readfirstlane (scalar starts/counts/rec loads); x4 unroll.
// ---------------------------------------------------------------------------
__global__ __launch_bounds__(256) void agg_nodes(
    const int2* __restrict__ recs, const int* __restrict__ starts,
    const int* __restrict__ counts, const unsigned short* __restrict__ h,
    const float* __restrict__ bias, float* __restrict__ out)
{
    int wid  = (blockIdx.x * 256 + threadIdx.x) >> 6;
    int node = __builtin_amdgcn_readfirstlane(wid);
    if (node >= NNODES) return;
    int lane = threadIdx.x & 63;

    float acc = bias[lane];
    int s0  = starts[node];
    int cnt = counts[node];
    int i = s0, e = s0 + cnt;

    for (; i + 3 < e; i += 4) {
        int2 r0 = recs[i + 0];
        int2 r1 = recs[i + 1];
        int2 r2 = recs[i + 2];
        int2 r3 = recs[i + 3];
        float v0 = bf2f(h[(r0.x & 0xFFFF) * D_OUT + lane]);
        float v1 = bf2f(h[(r1.x & 0xFFFF) * D_OUT + lane]);
        float v2 = bf2f(h[(r2.x & 0xFFFF) * D_OUT + lane]);
        float v3 = bf2f(h[(r3.x & 0xFFFF) * D_OUT + lane]);
        acc += __int_as_float(r0.y) * v0;
        acc += __int_as_float(r1.y) * v1;
        acc += __int_as_float(r2.y) * v2;
        acc += __int_as_float(r3.y) * v3;
    }
    for (; i < e; ++i) {
        int2 r = recs[i];
        acc += __int_as_float(r.y) * bf2f(h[(r.x & 0xFFFF) * D_OUT + lane]);
    }
    out[(long long)node * D_OUT + lane] = acc;
}

// ---------------------------------------------------------------------------
// Fallback path (ws too small): bias init + per-edge atomics
// ---------------------------------------------------------------------------
__global__ __launch_bounds__(256) void init_bias(
    float* __restrict__ out, const float* __restrict__ bias, int total)
{
    int i = blockIdx.x * blockDim.x + threadIdx.x;
    if (i < total) out[i] = bias[i & (D_OUT - 1)];
}

__global__ __launch_bounds__(256) void scatter_edges(
    const int* __restrict__ src, const int* __restrict__ dst,
    const float* __restrict__ wt, const unsigned short* __restrict__ h,
    float* __restrict__ out)
{
    long long gid = (long long)blockIdx.x * blockDim.x + threadIdx.x;
    int e    = (int)(gid >> 6);
    int lane = threadIdx.x & 63;
    if (e < NEDGES) {
        int   s = src[e];
        int   d = dst[e];
        float w = wt[e];
        float v = w * bf2f(h[(long long)s * D_OUT + lane]);
        atomicAdd(&out[(long long)d * D_OUT + lane], v);
    }
}

// ---------------------------------------------------------------------------
// Launch
// ---------------------------------------------------------------------------
extern "C" void kernel_launch(void* const* d_in, const int* in_sizes, int n_in,
                              void* d_out, int out_size, void* d_ws, size_t ws_size,
                              hipStream_t stream)
{
    const float* W     = (const float*)d_in[0];   // [64, 256]
    const float* bias  = (const float*)d_in[1];   // [64]
    const int*   edges = (const int*)  d_in[2];   // [2, E]
    const float* wt    = (const float*)d_in[3];   // [E]
    const float* x     = (const float*)d_in[4];   // [N, 256]
    float*       out   = (float*)d_out;           // [N, 64]

    const int* src = edges;
    const int* dst = edges + NEDGES;

    // workspace carve-up (bytes)
    char* ws = (char*)d_ws;
    const size_t OFF_H      = 0;                   // 6,400,000   (bf16 h)
    const size_t OFF_WB     = 6400000;             // 32,768     (bf16 W)
    const size_t OFF_RECS   = 6432768;             // 10,000,000 (CSR recs)
    const size_t OFF_STARTS = 16432768;            // 200,000
    const size_t OFF_COUNTS = 16632768;            // 200,000
    const size_t OFF_BCOUNT = 16832768;            // 12,544
    const size_t OFF_BCUR   = 16845312;            // 12,544
    const size_t OFF_BSTART = 16857856;            // 788
    const size_t REQUIRED   = 16858644;

    unsigned short* h  = (unsigned short*)(ws + OFF_H);
    unsigned short* Wb = (unsigned short*)(ws + OFF_WB);

    // 0) W -> bf16 (one-time, 16K elems)
    convert_w<<<(D_OUT * D_IN + 255) / 256, 256, 0, stream>>>(W, Wb);

    // 1) h = x @ W^T  (bf16 MFMA, LDS fragment-order W, bf16 out)
    gemm_h_mfma<<<(NNODES + 63) / 64, 256, 0, stream>>>(x, Wb, h, NNODES);

    if (ws_size >= REQUIRED) {
        unsigned long long* csr     = (unsigned long long*)(ws + OFF_RECS);
        int*                starts  = (int*)(ws + OFF_STARTS);
        int*                counts  = (int*)(ws + OFF_COUNTS);
        int*                bcount  = (int*)(ws + OFF_BCOUNT);
        int*                bcursor = (int*)(ws + OFF_BCUR);
        int*                bstart  = (int*)(ws + OFF_BSTART);

        // d_out doubles as scratch for bucket-binned recs (10 MB <= 12.8 MB);
        // agg_nodes fully overwrites it afterwards.
        unsigned long long* binned = (unsigned long long*)d_out;

        hipMemsetAsync(bcount, 0, NBUCK * CPAD * sizeof(int), stream);

        coarse_hist<<<NB_EDGE, 256, 0, stream>>>(dst, bcount);
        bucket_scan<<<1, 256, 0, stream>>>(bcount, bstart, bcursor);
        bin_edges<<<NB_EDGE, 256, 0, stream>>>(src, dst, wt, bcursor, binned);
        sort_buckets<<<NBUCK, 256, 0, stream>>>(binned, bstart, csr, starts, counts);

        int nb = (NNODES * 64 + 255) / 256;  // 12500 blocks, 4 nodes/block
        agg_nodes<<<nb, 256, 0, stream>>>((const int2*)csr, starts, counts, h, bias, out);
    } else {
        int total = NNODES * D_OUT;
        init_bias<<<(total + 255) / 256, 256, 0, stream>>>(out, bias, total);
        long long threads = (long long)NEDGES * 64;
        int blocks = (int)((threads + 255) / 256);
        scatter_edges<<<blocks, 256, 0, stream>>>(src, dst, wt, h, out);
    }
}

// Round 11
// 203.741 us; speedup vs baseline: 1.0270x; 1.0174x over previous
//
#include <hip/hip_runtime.h>
#include <hip/hip_bf16.h>

// Problem constants (from reference)
#define D_IN    256
#define D_OUT   64
#define NNODES  50000
#define NEDGES  1250000

#define BUCK_SHIFT 8                       // 256 nodes per bucket
#define BUCK_NODES 256
#define NBUCK      196                     // ceil(50000/256)
#define CPAD       16                      // pad counters to 64B lines
#define EPB        4096                    // edges per binning block
#define NB_EDGE    ((NEDGES + EPB - 1) / EPB)   // 306

typedef float f32x4 __attribute__((ext_vector_type(4)));
typedef short s16x8 __attribute__((ext_vector_type(8)));   // 8 bf16 (4 VGPRs)

// fp32 -> bf16 bits, round-to-nearest-even
static __device__ __forceinline__ unsigned short f2bf(float f) {
    union { float f; unsigned u; } v; v.f = f;
    unsigned r = v.u + 0x7FFFu + ((v.u >> 16) & 1u);
    return (unsigned short)(r >> 16);
}

// ---------------------------------------------------------------------------
// Kernel 0: one-time W fp32 -> bf16 (64x256 = 16K elements)
// ---------------------------------------------------------------------------
__global__ __launch_bounds__(256) void convert_w(
    const float* __restrict__ W, unsigned short* __restrict__ Wb)
{
    int i = blockIdx.x * 256 + threadIdx.x;
    if (i < D_OUT * D_IN) Wb[i] = f2bf(W[i]);
}

// ---------------------------------------------------------------------------
// Kernel 1: h = x @ W^T via bf16 MFMA (fp32 accum), OUTPUT = int8 rows with
// per-row scale. Rationale: bf16 h (6.4 MB, 128B rows) thrashes the 4 MiB
// per-XCD L2 and costs 2 lines per edge-gather; int8 h (3.2 MB, 64B rows)
// is L2-resident and costs exactly 1 line per edge. Row amax via 16-lane
// shfl_xor (lanes sharing q hold the row's 64 cols: col = c*16 + m).
// Scale is folded into edge weights later (bin_edges) -> agg needs no scale.
// ---------------------------------------------------------------------------
__global__ __launch_bounds__(256) void gemm_h_mfma(
    const float* __restrict__ x, const unsigned short* __restrict__ Wb,
    signed char* __restrict__ hq, float* __restrict__ scale_tab, int N)
{
    __shared__ uint4 sW[2048];   // 32 KB: 4 c * 8 kb * 64 lanes

    const int t    = threadIdx.x;
    const int lane = t & 63;
    const int wave = t >> 6;
    const int m    = lane & 15;
    const int q    = lane >> 4;

    // stage W fragments (gather from L2-resident 32 KB, store linear)
    #pragma unroll
    for (int i = 0; i < 8; ++i) {
        int slot = t + i * 256;
        int ln   = slot & 63;
        int kb   = (slot >> 6) & 7;
        int c    = slot >> 9;
        int lm = ln & 15, lq = ln >> 4;
        sW[slot] = ((const uint4*)Wb)[(c * 16 + lm) * 32 + kb * 4 + lq];
    }
    __syncthreads();

    const int rowA = blockIdx.x * 64 + wave * 16 + m;
    const int rowc = (rowA < N) ? rowA : (N - 1);
    const float* xr = x + (long long)rowc * D_IN + q * 8;

    f32x4 acc[4] = {};

    #pragma unroll
    for (int kb = 0; kb < 8; ++kb) {
        float4 a0 = *(const float4*)(xr + kb * 32);
        float4 a1 = *(const float4*)(xr + kb * 32 + 4);
        s16x8 af;
        af[0] = (short)f2bf(a0.x); af[1] = (short)f2bf(a0.y);
        af[2] = (short)f2bf(a0.z); af[3] = (short)f2bf(a0.w);
        af[4] = (short)f2bf(a1.x); af[5] = (short)f2bf(a1.y);
        af[6] = (short)f2bf(a1.z); af[7] = (short)f2bf(a1.w);

        #pragma unroll
        for (int c = 0; c < 4; ++c) {
            s16x8 bf = *(const s16x8*)&sW[(c * 8 + kb) * 64 + lane];
            acc[c] = __builtin_amdgcn_mfma_f32_16x16x32_bf16(af, bf, acc[c], 0, 0, 0);
        }
    }

    // Epilogue: per-row amax -> int8 quantize. Row gr = blk*64+wave*16+q*4+r
    // is held by the 16 lanes with the same q (m = 0..15), 4 regs (c) each.
    #pragma unroll
    for (int r = 0; r < 4; ++r) {
        float local = fmaxf(fmaxf(fabsf(acc[0][r]), fabsf(acc[1][r])),
                            fmaxf(fabsf(acc[2][r]), fabsf(acc[3][r])));
        #pragma unroll
        for (int msk = 1; msk < 16; msk <<= 1)
            local = fmaxf(local, __shfl_xor(local, msk));
        float amax = fmaxf(local, 1e-6f);
        float inv  = 127.0f / amax;
        int gr = blockIdx.x * 64 + wave * 16 + q * 4 + r;
        if (gr < N) {
            if (m == 0) scale_tab[gr] = amax * (1.0f / 127.0f);
            #pragma unroll
            for (int c = 0; c < 4; ++c) {
                int qv = __float2int_rn(acc[c][r] * inv);
                hq[(long long)gr * D_OUT + c * 16 + m] = (signed char)qv;
            }
        }
    }
}

// ---------------------------------------------------------------------------
// Kernel 2: coarse histogram over 196 buckets (LDS-private, one padded
// global atomic per block-bucket).
// ---------------------------------------------------------------------------
__global__ __launch_bounds__(256) void coarse_hist(
    const int* __restrict__ dst, int* __restrict__ bcount)
{
    __shared__ int lh[NBUCK];
    int t = threadIdx.x;
    for (int i = t; i < NBUCK; i += 256) lh[i] = 0;
    __syncthreads();
    int base = blockIdx.x * EPB;
    int end  = min(base + EPB, NEDGES);
    for (int e = base + t; e < end; e += 256)
        atomicAdd(&lh[dst[e] >> BUCK_SHIFT], 1);
    __syncthreads();
    if (t < NBUCK) {
        int c = lh[t];
        if (c) atomicAdd(&bcount[t * CPAD], c);
    }
}

// ---------------------------------------------------------------------------
// Kernel 3: single-block scan of bucket counts -> bstart[NBUCK+1] + cursors.
// ---------------------------------------------------------------------------
__global__ __launch_bounds__(256) void bucket_scan(
    const int* __restrict__ bcount, int* __restrict__ bstart,
    int* __restrict__ bcursor)
{
    int t = threadIdx.x;
    int v = (t < NBUCK) ? bcount[t * CPAD] : 0;
    __shared__ int s[256];
    s[t] = v; __syncthreads();
    #pragma unroll
    for (int off = 1; off < 256; off <<= 1) {
        int u = (t >= off) ? s[t - off] : 0;
        __syncthreads();
        s[t] += u;
        __syncthreads();
    }
    if (t < NBUCK) {
        int st = s[t] - v;
        bstart[t] = st;
        bcursor[t * CPAD] = st;
    }
    if (t == 0) bstart[NBUCK] = NEDGES;
}

// ---------------------------------------------------------------------------
// Kernel 4: bin edges into bucket-grouped regions. The per-row h scale is
// FOLDED into the record weight here (scale_tab gather is L2-hot, 200 KB).
// rec = [wt*scale[src]:32 | dst_local:8 (bits16..23) | src:16 (lo)]
// ---------------------------------------------------------------------------
__global__ __launch_bounds__(256) void bin_edges(
    const int* __restrict__ src, const int* __restrict__ dst,
    const float* __restrict__ wt, const float* __restrict__ scale_tab,
    int* __restrict__ bcursor, unsigned long long* __restrict__ binned)
{
    __shared__ int lcnt[NBUCK];
    __shared__ int lbase[NBUCK];
    int t = threadIdx.x;
    for (int i = t; i < NBUCK; i += 256) lcnt[i] = 0;
    __syncthreads();

    int base = blockIdx.x * EPB;
    int end  = min(base + EPB, NEDGES);

    for (int e = base + t; e < end; e += 256)
        atomicAdd(&lcnt[dst[e] >> BUCK_SHIFT], 1);
    __syncthreads();

    if (t < NBUCK) {
        int c = lcnt[t];
        lbase[t] = c ? atomicAdd(&bcursor[t * CPAD], c) : 0;
        lcnt[t]  = 0;   // reuse as local rank counter
    }
    __syncthreads();

    for (int e = base + t; e < end; e += 256) {
        int d = dst[e];
        int b = d >> BUCK_SHIFT;
        int r = atomicAdd(&lcnt[b], 1);
        int s = src[e];
        float wf = wt[e] * scale_tab[s];
        unsigned lo = (unsigned)s | ((unsigned)(d & (BUCK_NODES - 1)) << 16);
        unsigned long long rec = (unsigned long long)lo
                               | ((unsigned long long)__float_as_uint(wf) << 32);
        binned[lbase[b] + r] = rec;
    }
}

// ---------------------------------------------------------------------------
// Kernel 5: per-bucket counting sort to per-node CSR. One block per bucket;
// streaming: count 256 local nodes in LDS, scan, write starts/counts,
// scatter recs from binned (d_out) into csr (ws).
// ---------------------------------------------------------------------------
__global__ __launch_bounds__(256) void sort_buckets(
    const unsigned long long* __restrict__ binned, const int* __restrict__ bstart,
    unsigned long long* __restrict__ csr,
    int* __restrict__ starts, int* __restrict__ counts)
{
    __shared__ int lcnt[BUCK_NODES];
    __shared__ int lcur[BUCK_NODES];
    __shared__ int s[256];
    int t = threadIdx.x;
    int b = blockIdx.x;
    int s0 = bstart[b];
    int e0 = bstart[b + 1];
    int node0 = b << BUCK_SHIFT;
    int nn = min(BUCK_NODES, NNODES - node0);

    lcnt[t] = 0;
    __syncthreads();

    for (int k = s0 + t; k < e0; k += 256)
        atomicAdd(&lcnt[(int)((binned[k] >> 16) & 0xFF)], 1);
    __syncthreads();

    int v = lcnt[t];
    s[t] = v; __syncthreads();
    #pragma unroll
    for (int off = 1; off < 256; off <<= 1) {
        int u = (t >= off) ? s[t - off] : 0;
        __syncthreads();
        s[t] += u;
        __syncthreads();
    }
    int excl = s[t] - v;
    lcur[t] = s0 + excl;          // absolute cursor within bucket region
    if (t < nn) {
        starts[node0 + t] = s0 + excl;
        counts[node0 + t] = v;
    }
    __syncthreads();

    for (int k = s0 + t; k < e0; k += 256) {
        unsigned long long r = binned[k];
        int dloc = (int)((r >> 16) & 0xFF);
        int pos  = atomicAdd(&lcur[dloc], 1);
        csr[pos] = r;
    }
}

// ---------------------------------------------------------------------------
// Kernel 6: aggregation. One wave per node, lane = output column, node in
// SGPR via readfirstlane; x4 unroll. int8 h gather: 64B row = ONE cache
// line per edge (was two with bf16); scale already folded into rec weight.
// ---------------------------------------------------------------------------
__global__ __launch_bounds__(256) void agg_nodes(
    const int2* __restrict__ recs, const int* __restrict__ starts,
    const int* __restrict__ counts, const signed char* __restrict__ hq,
    const float* __restrict__ bias, float* __restrict__ out)
{
    int wid  = (blockIdx.x * 256 + threadIdx.x) >> 6;
    int node = __builtin_amdgcn_readfirstlane(wid);
    if (node >= NNODES) return;
    int lane = threadIdx.x & 63;

    float acc = bias[lane];
    int s0  = starts[node];
    int cnt = counts[node];
    int i = s0, e = s0 + cnt;

    for (; i + 3 < e; i += 4) {
        int2 r0 = recs[i + 0];
        int2 r1 = recs[i + 1];
        int2 r2 = recs[i + 2];
        int2 r3 = recs[i + 3];
        float v0 = (float)hq[(r0.x & 0xFFFF) * D_OUT + lane];
        float v1 = (float)hq[(r1.x & 0xFFFF) * D_OUT + lane];
        float v2 = (float)hq[(r2.x & 0xFFFF) * D_OUT + lane];
        float v3 = (float)hq[(r3.x & 0xFFFF) * D_OUT + lane];
        acc += __int_as_float(r0.y) * v0;
        acc += __int_as_float(r1.y) * v1;
        acc += __int_as_float(r2.y) * v2;
        acc += __int_as_float(r3.y) * v3;
    }
    for (; i < e; ++i) {
        int2 r = recs[i];
        acc += __int_as_float(r.y) * (float)hq[(r.x & 0xFFFF) * D_OUT + lane];
    }
    out[(long long)node * D_OUT + lane] = acc;
}

// ---------------------------------------------------------------------------
// Fallback path (ws too small): bias init + per-edge atomics (int8 h)
// ---------------------------------------------------------------------------
__global__ __launch_bounds__(256) void init_bias(
    float* __restrict__ out, const float* __restrict__ bias, int total)
{
    int i = blockIdx.x * blockDim.x + threadIdx.x;
    if (i < total) out[i] = bias[i & (D_OUT - 1)];
}

__global__ __launch_bounds__(256) void scatter_edges(
    const int* __restrict__ src, const int* __restrict__ dst,
    const float* __restrict__ wt, const signed char* __restrict__ hq,
    const float* __restrict__ scale_tab, float* __restrict__ out)
{
    long long gid = (long long)blockIdx.x * blockDim.x + threadIdx.x;
    int e    = (int)(gid >> 6);
    int lane = threadIdx.x & 63;
    if (e < NEDGES) {
        int   s = src[e];
        int   d = dst[e];
        float w = wt[e] * scale_tab[s];
        float v = w * (float)hq[(long long)s * D_OUT + lane];
        atomicAdd(&out[(long long)d * D_OUT + lane], v);
    }
}

// ---------------------------------------------------------------------------
// Launch
// ---------------------------------------------------------------------------
extern "C" void kernel_launch(void* const* d_in, const int* in_sizes, int n_in,
                              void* d_out, int out_size, void* d_ws, size_t ws_size,
                              hipStream_t stream)
{
    const float* W     = (const float*)d_in[0];   // [64, 256]
    const float* bias  = (const float*)d_in[1];   // [64]
    const int*   edges = (const int*)  d_in[2];   // [2, E]
    const float* wt    = (const float*)d_in[3];   // [E]
    const float* x     = (const float*)d_in[4];   // [N, 256]
    float*       out   = (float*)d_out;           // [N, 64]

    const int* src = edges;
    const int* dst = edges + NEDGES;

    // workspace carve-up (bytes)
    char* ws = (char*)d_ws;
    const size_t OFF_HQ     = 0;                   // 3,200,000  (int8 h)
    const size_t OFF_SCALE  = 3200000;             // 200,000    (fp32 row scales)
    const size_t OFF_WB     = 3400000;             // 32,768     (bf16 W)
    const size_t OFF_RECS   = 3432768;             // 10,000,000 (CSR recs)
    const size_t OFF_STARTS = 13432768;            // 200,000
    const size_t OFF_COUNTS = 13632768;            // 200,000
    const size_t OFF_BCOUNT = 13832768;            // 12,544
    const size_t OFF_BCUR   = 13845312;            // 12,544
    const size_t OFF_BSTART = 13857856;            // 788
    const size_t REQUIRED   = 13858644;

    signed char*    hq        = (signed char*)(ws + OFF_HQ);
    float*          scale_tab = (float*)(ws + OFF_SCALE);
    unsigned short* Wb        = (unsigned short*)(ws + OFF_WB);

    // 0) W -> bf16 (one-time, 16K elems)
    convert_w<<<(D_OUT * D_IN + 255) / 256, 256, 0, stream>>>(W, Wb);

    // 1) h = x @ W^T  (bf16 MFMA, int8 row-quantized output + scales)
    gemm_h_mfma<<<(NNODES + 63) / 64, 256, 0, stream>>>(x, Wb, hq, scale_tab, NNODES);

    if (ws_size >= REQUIRED) {
        unsigned long long* csr     = (unsigned long long*)(ws + OFF_RECS);
        int*                starts  = (int*)(ws + OFF_STARTS);
        int*                counts  = (int*)(ws + OFF_COUNTS);
        int*                bcount  = (int*)(ws + OFF_BCOUNT);
        int*                bcursor = (int*)(ws + OFF_BCUR);
        int*                bstart  = (int*)(ws + OFF_BSTART);

        // d_out doubles as scratch for bucket-binned recs (10 MB <= 12.8 MB);
        // agg_nodes fully overwrites it afterwards.
        unsigned long long* binned = (unsigned long long*)d_out;

        hipMemsetAsync(bcount, 0, NBUCK * CPAD * sizeof(int), stream);

        coarse_hist<<<NB_EDGE, 256, 0, stream>>>(dst, bcount);
        bucket_scan<<<1, 256, 0, stream>>>(bcount, bstart, bcursor);
        bin_edges<<<NB_EDGE, 256, 0, stream>>>(src, dst, wt, scale_tab, bcursor, binned);
        sort_buckets<<<NBUCK, 256, 0, stream>>>(binned, bstart, csr, starts, counts);

        int nb = (NNODES * 64 + 255) / 256;  // 12500 blocks, 4 nodes/block
        agg_nodes<<<nb, 256, 0, stream>>>((const int2*)csr, starts, counts, hq, bias, out);
    } else {
        int total = NNODES * D_OUT;
        init_bias<<<(total + 255) / 256, 256, 0, stream>>>(out, bias, total);
        long long threads = (long long)NEDGES * 64;
        int blocks = (int)((threads + 255) / 256);
        scatter_edges<<<blocks, 256, 0, stream>>>(src, dst, wt, hq, scale_tab, out);
    }
}

// Round 12
// 196.553 us; speedup vs baseline: 1.0645x; 1.0366x over previous
//
#include <hip/hip_runtime.h>
#include <hip/hip_bf16.h>

// Problem constants (from reference)
#define D_IN    256
#define D_OUT   64
#define NNODES  50000
#define NEDGES  1250000

#define BUCK_SHIFT 8                       // 256 nodes per bucket
#define BUCK_NODES 256
#define NBUCK      196                     // ceil(50000/256)
#define CPAD       16                      // pad counters to 64B lines
#define EPB        4096                    // edges per binning block
#define NB_EDGE    ((NEDGES + EPB - 1) / EPB)   // 306

typedef float f32x4 __attribute__((ext_vector_type(4)));
typedef short s16x8 __attribute__((ext_vector_type(8)));   // 8 bf16 (4 VGPRs)

// fp32 -> bf16 bits, round-to-nearest-even
static __device__ __forceinline__ unsigned short f2bf(float f) {
    union { float f; unsigned u; } v; v.f = f;
    unsigned r = v.u + 0x7FFFu + ((v.u >> 16) & 1u);
    return (unsigned short)(r >> 16);
}

// ---------------------------------------------------------------------------
// Kernel 0: one-time W fp32 -> bf16 (64x256 = 16K elements)
// ---------------------------------------------------------------------------
__global__ __launch_bounds__(256) void convert_w(
    const float* __restrict__ W, unsigned short* __restrict__ Wb)
{
    int i = blockIdx.x * 256 + threadIdx.x;
    if (i < D_OUT * D_IN) Wb[i] = f2bf(W[i]);
}

// ---------------------------------------------------------------------------
// Kernel 1: h = x @ W^T via bf16 MFMA (fp32 accum), int8 output + per-row
// scale (folded into edge weights in bin_edges). hq = 3.2 MB, 64B rows ->
// 1 cache line per edge-gather, per-XCD-L2 resident.
// ---------------------------------------------------------------------------
__global__ __launch_bounds__(256) void gemm_h_mfma(
    const float* __restrict__ x, const unsigned short* __restrict__ Wb,
    signed char* __restrict__ hq, float* __restrict__ scale_tab, int N)
{
    __shared__ uint4 sW[2048];   // 32 KB: 4 c * 8 kb * 64 lanes

    const int t    = threadIdx.x;
    const int lane = t & 63;
    const int wave = t >> 6;
    const int m    = lane & 15;
    const int q    = lane >> 4;

    #pragma unroll
    for (int i = 0; i < 8; ++i) {
        int slot = t + i * 256;
        int ln   = slot & 63;
        int kb   = (slot >> 6) & 7;
        int c    = slot >> 9;
        int lm = ln & 15, lq = ln >> 4;
        sW[slot] = ((const uint4*)Wb)[(c * 16 + lm) * 32 + kb * 4 + lq];
    }
    __syncthreads();

    const int rowA = blockIdx.x * 64 + wave * 16 + m;
    const int rowc = (rowA < N) ? rowA : (N - 1);
    const float* xr = x + (long long)rowc * D_IN + q * 8;

    f32x4 acc[4] = {};

    #pragma unroll
    for (int kb = 0; kb < 8; ++kb) {
        float4 a0 = *(const float4*)(xr + kb * 32);
        float4 a1 = *(const float4*)(xr + kb * 32 + 4);
        s16x8 af;
        af[0] = (short)f2bf(a0.x); af[1] = (short)f2bf(a0.y);
        af[2] = (short)f2bf(a0.z); af[3] = (short)f2bf(a0.w);
        af[4] = (short)f2bf(a1.x); af[5] = (short)f2bf(a1.y);
        af[6] = (short)f2bf(a1.z); af[7] = (short)f2bf(a1.w);

        #pragma unroll
        for (int c = 0; c < 4; ++c) {
            s16x8 bf = *(const s16x8*)&sW[(c * 8 + kb) * 64 + lane];
            acc[c] = __builtin_amdgcn_mfma_f32_16x16x32_bf16(af, bf, acc[c], 0, 0, 0);
        }
    }

    // Epilogue: per-row amax (16-lane shfl_xor across m) -> int8 quantize.
    #pragma unroll
    for (int r = 0; r < 4; ++r) {
        float local = fmaxf(fmaxf(fabsf(acc[0][r]), fabsf(acc[1][r])),
                            fmaxf(fabsf(acc[2][r]), fabsf(acc[3][r])));
        #pragma unroll
        for (int msk = 1; msk < 16; msk <<= 1)
            local = fmaxf(local, __shfl_xor(local, msk));
        float amax = fmaxf(local, 1e-6f);
        float inv  = 127.0f / amax;
        int gr = blockIdx.x * 64 + wave * 16 + q * 4 + r;
        if (gr < N) {
            if (m == 0) scale_tab[gr] = amax * (1.0f / 127.0f);
            #pragma unroll
            for (int c = 0; c < 4; ++c) {
                int qv = __float2int_rn(acc[c][r] * inv);
                hq[(long long)gr * D_OUT + c * 16 + m] = (signed char)qv;
            }
        }
    }
}

// ---------------------------------------------------------------------------
// Kernel 2: coarse histogram over 196 buckets. Full blocks (4096 edges,
// 16B-aligned base) read dst via int4 -> 4x fewer VMEM instructions.
// ---------------------------------------------------------------------------
__global__ __launch_bounds__(256) void coarse_hist(
    const int* __restrict__ dst, int* __restrict__ bcount)
{
    __shared__ int lh[NBUCK];
    int t = threadIdx.x;
    for (int i = t; i < NBUCK; i += 256) lh[i] = 0;
    __syncthreads();
    int base = blockIdx.x * EPB;
    if (base + EPB <= NEDGES) {
        const int4* d4 = (const int4*)(dst + base);
        #pragma unroll
        for (int it = 0; it < 4; ++it) {
            int4 d = d4[t + it * 256];
            atomicAdd(&lh[d.x >> BUCK_SHIFT], 1);
            atomicAdd(&lh[d.y >> BUCK_SHIFT], 1);
            atomicAdd(&lh[d.z >> BUCK_SHIFT], 1);
            atomicAdd(&lh[d.w >> BUCK_SHIFT], 1);
        }
    } else {
        int end = NEDGES;
        for (int e = base + t; e < end; e += 256)
            atomicAdd(&lh[dst[e] >> BUCK_SHIFT], 1);
    }
    __syncthreads();
    if (t < NBUCK) {
        int c = lh[t];
        if (c) atomicAdd(&bcount[t * CPAD], c);
    }
}

// ---------------------------------------------------------------------------
// Kernel 3: single-block scan of bucket counts -> bstart[NBUCK+1] + cursors.
// ---------------------------------------------------------------------------
__global__ __launch_bounds__(256) void bucket_scan(
    const int* __restrict__ bcount, int* __restrict__ bstart,
    int* __restrict__ bcursor)
{
    int t = threadIdx.x;
    int v = (t < NBUCK) ? bcount[t * CPAD] : 0;
    __shared__ int s[256];
    s[t] = v; __syncthreads();
    #pragma unroll
    for (int off = 1; off < 256; off <<= 1) {
        int u = (t >= off) ? s[t - off] : 0;
        __syncthreads();
        s[t] += u;
        __syncthreads();
    }
    if (t < NBUCK) {
        int st = s[t] - v;
        bstart[t] = st;
        bcursor[t * CPAD] = st;
    }
    if (t == 0) bstart[NBUCK] = NEDGES;
}

// ---------------------------------------------------------------------------
// Kernel 4: bin edges into bucket-grouped regions. Vectorized int4/float4
// edge-stream loads in both phases (full blocks); per-row h scale folded
// into the record weight. rec = [wt*scale:32 | dst_local:8 | src:16]
// ---------------------------------------------------------------------------
__global__ __launch_bounds__(256) void bin_edges(
    const int* __restrict__ src, const int* __restrict__ dst,
    const float* __restrict__ wt, const float* __restrict__ scale_tab,
    int* __restrict__ bcursor, unsigned long long* __restrict__ binned)
{
    __shared__ int lcnt[NBUCK];
    __shared__ int lbase[NBUCK];
    int t = threadIdx.x;
    for (int i = t; i < NBUCK; i += 256) lcnt[i] = 0;
    __syncthreads();

    int base = blockIdx.x * EPB;
    bool full = (base + EPB <= NEDGES);

    // phase 1: local bucket counts
    if (full) {
        const int4* d4 = (const int4*)(dst + base);
        #pragma unroll
        for (int it = 0; it < 4; ++it) {
            int4 d = d4[t + it * 256];
            atomicAdd(&lcnt[d.x >> BUCK_SHIFT], 1);
            atomicAdd(&lcnt[d.y >> BUCK_SHIFT], 1);
            atomicAdd(&lcnt[d.z >> BUCK_SHIFT], 1);
            atomicAdd(&lcnt[d.w >> BUCK_SHIFT], 1);
        }
    } else {
        for (int e = base + t; e < NEDGES; e += 256)
            atomicAdd(&lcnt[dst[e] >> BUCK_SHIFT], 1);
    }
    __syncthreads();

    // phase 2: reserve global ranges
    if (t < NBUCK) {
        int c = lcnt[t];
        lbase[t] = c ? atomicAdd(&bcursor[t * CPAD], c) : 0;
        lcnt[t]  = 0;   // reuse as local rank counter
    }
    __syncthreads();

    // phase 3: scatter packed records
    if (full) {
        const int4*   s4 = (const int4*)(src + base);
        const int4*   d4 = (const int4*)(dst + base);
        const float4* w4 = (const float4*)(wt + base);
        #pragma unroll
        for (int it = 0; it < 4; ++it) {
            int4   ss = s4[t + it * 256];
            int4   dd = d4[t + it * 256];
            float4 ww = w4[t + it * 256];
            int sv[4]   = {ss.x, ss.y, ss.z, ss.w};
            int dv[4]   = {dd.x, dd.y, dd.z, dd.w};
            float wv[4] = {ww.x, ww.y, ww.z, ww.w};
            #pragma unroll
            for (int k = 0; k < 4; ++k) {
                int d = dv[k];
                int b = d >> BUCK_SHIFT;
                int r = atomicAdd(&lcnt[b], 1);
                float wf = wv[k] * scale_tab[sv[k]];
                unsigned lo = (unsigned)sv[k] | ((unsigned)(d & (BUCK_NODES - 1)) << 16);
                unsigned long long rec = (unsigned long long)lo
                                       | ((unsigned long long)__float_as_uint(wf) << 32);
                binned[lbase[b] + r] = rec;
            }
        }
    } else {
        for (int e = base + t; e < NEDGES; e += 256) {
            int d = dst[e];
            int b = d >> BUCK_SHIFT;
            int r = atomicAdd(&lcnt[b], 1);
            int s = src[e];
            float wf = wt[e] * scale_tab[s];
            unsigned lo = (unsigned)s | ((unsigned)(d & (BUCK_NODES - 1)) << 16);
            unsigned long long rec = (unsigned long long)lo
                                   | ((unsigned long long)__float_as_uint(wf) << 32);
            binned[lbase[b] + r] = rec;
        }
    }
}

// ---------------------------------------------------------------------------
// Kernel 5: per-bucket counting sort to per-node CSR (unchanged, verified).
// ---------------------------------------------------------------------------
__global__ __launch_bounds__(256) void sort_buckets(
    const unsigned long long* __restrict__ binned, const int* __restrict__ bstart,
    unsigned long long* __restrict__ csr,
    int* __restrict__ starts, int* __restrict__ counts)
{
    __shared__ int lcnt[BUCK_NODES];
    __shared__ int lcur[BUCK_NODES];
    __shared__ int s[256];
    int t = threadIdx.x;
    int b = blockIdx.x;
    int s0 = bstart[b];
    int e0 = bstart[b + 1];
    int node0 = b << BUCK_SHIFT;
    int nn = min(BUCK_NODES, NNODES - node0);

    lcnt[t] = 0;
    __syncthreads();

    for (int k = s0 + t; k < e0; k += 256)
        atomicAdd(&lcnt[(int)((binned[k] >> 16) & 0xFF)], 1);
    __syncthreads();

    int v = lcnt[t];
    s[t] = v; __syncthreads();
    #pragma unroll
    for (int off = 1; off < 256; off <<= 1) {
        int u = (t >= off) ? s[t - off] : 0;
        __syncthreads();
        s[t] += u;
        __syncthreads();
    }
    int excl = s[t] - v;
    lcur[t] = s0 + excl;
    if (t < nn) {
        starts[node0 + t] = s0 + excl;
        counts[node0 + t] = v;
    }
    __syncthreads();

    for (int k = s0 + t; k < e0; k += 256) {
        unsigned long long r = binned[k];
        int dloc = (int)((r >> 16) & 0xFF);
        int pos  = atomicAdd(&lcur[dloc], 1);
        csr[pos] = r;
    }
}

// ---------------------------------------------------------------------------
// Kernel 6: aggregation. One wave per node, lane = output column, node in
// SGPR via readfirstlane. x8 unroll -> 8 independent 64B-row gathers in
// flight per wave (attacks the latency-batch product). Scale pre-folded.
// ---------------------------------------------------------------------------
__global__ __launch_bounds__(256) void agg_nodes(
    const int2* __restrict__ recs, const int* __restrict__ starts,
    const int* __restrict__ counts, const signed char* __restrict__ hq,
    const float* __restrict__ bias, float* __restrict__ out)
{
    int wid  = (blockIdx.x * 256 + threadIdx.x) >> 6;
    int node = __builtin_amdgcn_readfirstlane(wid);
    if (node >= NNODES) return;
    int lane = threadIdx.x & 63;

    float acc = bias[lane];
    int s0  = starts[node];
    int cnt = counts[node];
    int i = s0, e = s0 + cnt;

    for (; i + 7 < e; i += 8) {
        int2 r0 = recs[i + 0];
        int2 r1 = recs[i + 1];
        int2 r2 = recs[i + 2];
        int2 r3 = recs[i + 3];
        int2 r4 = recs[i + 4];
        int2 r5 = recs[i + 5];
        int2 r6 = recs[i + 6];
        int2 r7 = recs[i + 7];
        float v0 = (float)hq[(r0.x & 0xFFFF) * D_OUT + lane];
        float v1 = (float)hq[(r1.x & 0xFFFF) * D_OUT + lane];
        float v2 = (float)hq[(r2.x & 0xFFFF) * D_OUT + lane];
        float v3 = (float)hq[(r3.x & 0xFFFF) * D_OUT + lane];
        float v4 = (float)hq[(r4.x & 0xFFFF) * D_OUT + lane];
        float v5 = (float)hq[(r5.x & 0xFFFF) * D_OUT + lane];
        float v6 = (float)hq[(r6.x & 0xFFFF) * D_OUT + lane];
        float v7 = (float)hq[(r7.x & 0xFFFF) * D_OUT + lane];
        acc += __int_as_float(r0.y) * v0;
        acc += __int_as_float(r1.y) * v1;
        acc += __int_as_float(r2.y) * v2;
        acc += __int_as_float(r3.y) * v3;
        acc += __int_as_float(r4.y) * v4;
        acc += __int_as_float(r5.y) * v5;
        acc += __int_as_float(r6.y) * v6;
        acc += __int_as_float(r7.y) * v7;
    }
    for (; i + 3 < e; i += 4) {
        int2 r0 = recs[i + 0];
        int2 r1 = recs[i + 1];
        int2 r2 = recs[i + 2];
        int2 r3 = recs[i + 3];
        float v0 = (float)hq[(r0.x & 0xFFFF) * D_OUT + lane];
        float v1 = (float)hq[(r1.x & 0xFFFF) * D_OUT + lane];
        float v2 = (float)hq[(r2.x & 0xFFFF) * D_OUT + lane];
        float v3 = (float)hq[(r3.x & 0xFFFF) * D_OUT + lane];
        acc += __int_as_float(r0.y) * v0;
        acc += __int_as_float(r1.y) * v1;
        acc += __int_as_float(r2.y) * v2;
        acc += __int_as_float(r3.y) * v3;
    }
    for (; i < e; ++i) {
        int2 r = recs[i];
        acc += __int_as_float(r.y) * (float)hq[(r.x & 0xFFFF) * D_OUT + lane];
    }
    out[(long long)node * D_OUT + lane] = acc;
}

// ---------------------------------------------------------------------------
// Fallback path (ws too small): bias init + per-edge atomics (int8 h)
// ---------------------------------------------------------------------------
__global__ __launch_bounds__(256) void init_bias(
    float* __restrict__ out, const float* __restrict__ bias, int total)
{
    int i = blockIdx.x * blockDim.x + threadIdx.x;
    if (i < total) out[i] = bias[i & (D_OUT - 1)];
}

__global__ __launch_bounds__(256) void scatter_edges(
    const int* __restrict__ src, const int* __restrict__ dst,
    const float* __restrict__ wt, const signed char* __restrict__ hq,
    const float* __restrict__ scale_tab, float* __restrict__ out)
{
    long long gid = (long long)blockIdx.x * blockDim.x + threadIdx.x;
    int e    = (int)(gid >> 6);
    int lane = threadIdx.x & 63;
    if (e < NEDGES) {
        int   s = src[e];
        int   d = dst[e];
        float w = wt[e] * scale_tab[s];
        float v = w * (float)hq[(long long)s * D_OUT + lane];
        atomicAdd(&out[(long long)d * D_OUT + lane], v);
    }
}

// ---------------------------------------------------------------------------
// Launch
// ---------------------------------------------------------------------------
extern "C" void kernel_launch(void* const* d_in, const int* in_sizes, int n_in,
                              void* d_out, int out_size, void* d_ws, size_t ws_size,
                              hipStream_t stream)
{
    const float* W     = (const float*)d_in[0];   // [64, 256]
    const float* bias  = (const float*)d_in[1];   // [64]
    const int*   edges = (const int*)  d_in[2];   // [2, E]
    const float* wt    = (const float*)d_in[3];   // [E]
    const float* x     = (const float*)d_in[4];   // [N, 256]
    float*       out   = (float*)d_out;           // [N, 64]

    const int* src = edges;
    const int* dst = edges + NEDGES;

    // workspace carve-up (bytes)
    char* ws = (char*)d_ws;
    const size_t OFF_HQ     = 0;                   // 3,200,000  (int8 h)
    const size_t OFF_SCALE  = 3200000;             // 200,000    (fp32 row scales)
    const size_t OFF_WB     = 3400000;             // 32,768     (bf16 W)
    const size_t OFF_RECS   = 3432768;             // 10,000,000 (CSR recs)
    const size_t OFF_STARTS = 13432768;            // 200,000
    const size_t OFF_COUNTS = 13632768;            // 200,000
    const size_t OFF_BCOUNT = 13832768;            // 12,544
    const size_t OFF_BCUR   = 13845312;            // 12,544
    const size_t OFF_BSTART = 13857856;            // 788
    const size_t REQUIRED   = 13858644;

    signed char*    hq        = (signed char*)(ws + OFF_HQ);
    float*          scale_tab = (float*)(ws + OFF_SCALE);
    unsigned short* Wb        = (unsigned short*)(ws + OFF_WB);

    // 0) W -> bf16 (one-time, 16K elems)
    convert_w<<<(D_OUT * D_IN + 255) / 256, 256, 0, stream>>>(W, Wb);

    // 1) h = x @ W^T  (bf16 MFMA, int8 row-quantized output + scales)
    gemm_h_mfma<<<(NNODES + 63) / 64, 256, 0, stream>>>(x, Wb, hq, scale_tab, NNODES);

    if (ws_size >= REQUIRED) {
        unsigned long long* csr     = (unsigned long long*)(ws + OFF_RECS);
        int*                starts  = (int*)(ws + OFF_STARTS);
        int*                counts  = (int*)(ws + OFF_COUNTS);
        int*                bcount  = (int*)(ws + OFF_BCOUNT);
        int*                bcursor = (int*)(ws + OFF_BCUR);
        int*                bstart  = (int*)(ws + OFF_BSTART);

        // d_out doubles as scratch for bucket-binned recs (10 MB <= 12.8 MB);
        // agg_nodes fully overwrites it afterwards.
        unsigned long long* binned = (unsigned long long*)d_out;

        hipMemsetAsync(bcount, 0, NBUCK * CPAD * sizeof(int), stream);

        coarse_hist<<<NB_EDGE, 256, 0, stream>>>(dst, bcount);
        bucket_scan<<<1, 256, 0, stream>>>(bcount, bstart, bcursor);
        bin_edges<<<NB_EDGE, 256, 0, stream>>>(src, dst, wt, scale_tab, bcursor, binned);
        sort_buckets<<<NBUCK, 256, 0, stream>>>(binned, bstart, csr, starts, counts);

        int nb = (NNODES * 64 + 255) / 256;  // 12500 blocks, 4 nodes/block
        agg_nodes<<<nb, 256, 0, stream>>>((const int2*)csr, starts, counts, hq, bias, out);
    } else {
        int total = NNODES * D_OUT;
        init_bias<<<(total + 255) / 256, 256, 0, stream>>>(out, bias, total);
        long long threads = (long long)NEDGES * 64;
        int blocks = (int)((threads + 255) / 256);
        scatter_edges<<<blocks, 256, 0, stream>>>(src, dst, wt, hq, scale_tab, out);
    }
}

// Round 13
// 189.851 us; speedup vs baseline: 1.1021x; 1.0353x over previous
//
#include <hip/hip_runtime.h>
#include <hip/hip_bf16.h>

// Problem constants (from reference)
#define D_IN    256
#define D_OUT   64
#define NNODES  50000
#define NEDGES  1250000

#define BUCK_SHIFT 8                       // 256 nodes per bucket
#define BUCK_NODES 256
#define NBUCK      196                     // ceil(50000/256)
#define CPAD       16                      // pad counters to 64B lines
#define EPB        4096                    // edges per binning block
#define NB_EDGE    ((NEDGES + EPB - 1) / EPB)   // 306

typedef float f32x4 __attribute__((ext_vector_type(4)));
typedef short s16x8 __attribute__((ext_vector_type(8)));   // 8 bf16 (4 VGPRs)

// fp32 -> bf16 bits, round-to-nearest-even
static __device__ __forceinline__ unsigned short f2bf(float f) {
    union { float f; unsigned u; } v; v.f = f;
    unsigned r = v.u + 0x7FFFu + ((v.u >> 16) & 1u);
    return (unsigned short)(r >> 16);
}

// ---------------------------------------------------------------------------
// Kernel 1: h = x @ W^T via bf16 MFMA (fp32 accum), int8 output + per-row
// scale. W converted fp32->bf16 DURING LDS staging (kills convert_w kernel
// and the Wb buffer); bcount+bcursor zeroed by block 0 (kills the memset
// dispatch — gemm strictly precedes coarse_hist on the stream).
// ---------------------------------------------------------------------------
__global__ __launch_bounds__(256) void gemm_h_mfma(
    const float* __restrict__ x, const float* __restrict__ W,
    signed char* __restrict__ hq, float* __restrict__ scale_tab,
    int* __restrict__ zero_buf, int zero_n, int N)
{
    __shared__ uint4 sW[2048];   // 32 KB: 4 c * 8 kb * 64 lanes

    const int t    = threadIdx.x;
    const int lane = t & 63;
    const int wave = t >> 6;
    const int m    = lane & 15;
    const int q    = lane >> 4;

    // block 0: zero the histogram/cursor counters for the CSR build
    if (zero_buf && blockIdx.x == 0) {
        for (int i = t; i < zero_n; i += 256) zero_buf[i] = 0;
    }

    // stage W fragments: read fp32 (L2-hot 64 KB), convert, pack bf16x8
    #pragma unroll
    for (int i = 0; i < 8; ++i) {
        int slot = t + i * 256;
        int ln   = slot & 63;
        int kb   = (slot >> 6) & 7;
        int c    = slot >> 9;
        int lm = ln & 15, lq = ln >> 4;
        const float* wp = W + (c * 16 + lm) * D_IN + kb * 32 + lq * 8;
        float4 w0 = *(const float4*)wp;
        float4 w1 = *(const float4*)(wp + 4);
        uint4 u;
        u.x = (unsigned)f2bf(w0.x) | ((unsigned)f2bf(w0.y) << 16);
        u.y = (unsigned)f2bf(w0.z) | ((unsigned)f2bf(w0.w) << 16);
        u.z = (unsigned)f2bf(w1.x) | ((unsigned)f2bf(w1.y) << 16);
        u.w = (unsigned)f2bf(w1.z) | ((unsigned)f2bf(w1.w) << 16);
        sW[slot] = u;
    }
    __syncthreads();

    const int rowA = blockIdx.x * 64 + wave * 16 + m;
    const int rowc = (rowA < N) ? rowA : (N - 1);
    const float* xr = x + (long long)rowc * D_IN + q * 8;

    f32x4 acc[4] = {};

    #pragma unroll
    for (int kb = 0; kb < 8; ++kb) {
        float4 a0 = *(const float4*)(xr + kb * 32);
        float4 a1 = *(const float4*)(xr + kb * 32 + 4);
        s16x8 af;
        af[0] = (short)f2bf(a0.x); af[1] = (short)f2bf(a0.y);
        af[2] = (short)f2bf(a0.z); af[3] = (short)f2bf(a0.w);
        af[4] = (short)f2bf(a1.x); af[5] = (short)f2bf(a1.y);
        af[6] = (short)f2bf(a1.z); af[7] = (short)f2bf(a1.w);

        #pragma unroll
        for (int c = 0; c < 4; ++c) {
            s16x8 bf = *(const s16x8*)&sW[(c * 8 + kb) * 64 + lane];
            acc[c] = __builtin_amdgcn_mfma_f32_16x16x32_bf16(af, bf, acc[c], 0, 0, 0);
        }
    }

    // Epilogue: per-row amax (16-lane shfl_xor across m) -> int8 quantize.
    #pragma unroll
    for (int r = 0; r < 4; ++r) {
        float local = fmaxf(fmaxf(fabsf(acc[0][r]), fabsf(acc[1][r])),
                            fmaxf(fabsf(acc[2][r]), fabsf(acc[3][r])));
        #pragma unroll
        for (int msk = 1; msk < 16; msk <<= 1)
            local = fmaxf(local, __shfl_xor(local, msk));
        float amax = fmaxf(local, 1e-6f);
        float inv  = 127.0f / amax;
        int gr = blockIdx.x * 64 + wave * 16 + q * 4 + r;
        if (gr < N) {
            if (m == 0) scale_tab[gr] = amax * (1.0f / 127.0f);
            #pragma unroll
            for (int c = 0; c < 4; ++c) {
                int qv = __float2int_rn(acc[c][r] * inv);
                hq[(long long)gr * D_OUT + c * 16 + m] = (signed char)qv;
            }
        }
    }
}

// ---------------------------------------------------------------------------
// Kernel 2: coarse histogram over 196 buckets. int4 edge reads (full blocks).
// ---------------------------------------------------------------------------
__global__ __launch_bounds__(256) void coarse_hist(
    const int* __restrict__ dst, int* __restrict__ bcount)
{
    __shared__ int lh[NBUCK];
    int t = threadIdx.x;
    for (int i = t; i < NBUCK; i += 256) lh[i] = 0;
    __syncthreads();
    int base = blockIdx.x * EPB;
    if (base + EPB <= NEDGES) {
        const int4* d4 = (const int4*)(dst + base);
        #pragma unroll
        for (int it = 0; it < 4; ++it) {
            int4 d = d4[t + it * 256];
            atomicAdd(&lh[d.x >> BUCK_SHIFT], 1);
            atomicAdd(&lh[d.y >> BUCK_SHIFT], 1);
            atomicAdd(&lh[d.z >> BUCK_SHIFT], 1);
            atomicAdd(&lh[d.w >> BUCK_SHIFT], 1);
        }
    } else {
        for (int e = base + t; e < NEDGES; e += 256)
            atomicAdd(&lh[dst[e] >> BUCK_SHIFT], 1);
    }
    __syncthreads();
    if (t < NBUCK) {
        int c = lh[t];
        if (c) atomicAdd(&bcount[t * CPAD], c);
    }
}

// ---------------------------------------------------------------------------
// Kernel 3: bin edges into bucket-grouped regions. Inline exclusive scan of
// bcount (196 L2-hot reads -> kills bucket_scan dispatch); bcursor holds
// RELATIVE offsets (zeroed by gemm). Vectorized int4/float4 streams.
// rec = [wt*scale[src]:32 | dst_local:8 | src:16]
// ---------------------------------------------------------------------------
__global__ __launch_bounds__(256) void bin_edges(
    const int* __restrict__ src, const int* __restrict__ dst,
    const float* __restrict__ wt, const float* __restrict__ scale_tab,
    const int* __restrict__ bcount, int* __restrict__ bcursor,
    unsigned long long* __restrict__ binned)
{
    __shared__ int s[256];
    __shared__ int bstartL[NBUCK];
    __shared__ int lcnt[NBUCK];
    __shared__ int lbase[NBUCK];
    int t = threadIdx.x;

    // inline exclusive scan of bucket counts
    int v = (t < NBUCK) ? bcount[t * CPAD] : 0;
    s[t] = v;
    for (int i = t; i < NBUCK; i += 256) lcnt[i] = 0;
    __syncthreads();
    #pragma unroll
    for (int off = 1; off < 256; off <<= 1) {
        int u = (t >= off) ? s[t - off] : 0;
        __syncthreads();
        s[t] += u;
        __syncthreads();
    }
    if (t < NBUCK) bstartL[t] = s[t] - v;
    __syncthreads();

    int base = blockIdx.x * EPB;
    bool full = (base + EPB <= NEDGES);

    // phase 1: local bucket counts
    if (full) {
        const int4* d4 = (const int4*)(dst + base);
        #pragma unroll
        for (int it = 0; it < 4; ++it) {
            int4 d = d4[t + it * 256];
            atomicAdd(&lcnt[d.x >> BUCK_SHIFT], 1);
            atomicAdd(&lcnt[d.y >> BUCK_SHIFT], 1);
            atomicAdd(&lcnt[d.z >> BUCK_SHIFT], 1);
            atomicAdd(&lcnt[d.w >> BUCK_SHIFT], 1);
        }
    } else {
        for (int e = base + t; e < NEDGES; e += 256)
            atomicAdd(&lcnt[dst[e] >> BUCK_SHIFT], 1);
    }
    __syncthreads();

    // phase 2: reserve global ranges (relative cursor + scanned base)
    if (t < NBUCK) {
        int c = lcnt[t];
        lbase[t] = c ? (bstartL[t] + atomicAdd(&bcursor[t * CPAD], c)) : 0;
        lcnt[t]  = 0;   // reuse as local rank counter
    }
    __syncthreads();

    // phase 3: scatter packed records
    if (full) {
        const int4*   s4 = (const int4*)(src + base);
        const int4*   d4 = (const int4*)(dst + base);
        const float4* w4 = (const float4*)(wt + base);
        #pragma unroll
        for (int it = 0; it < 4; ++it) {
            int4   ss = s4[t + it * 256];
            int4   dd = d4[t + it * 256];
            float4 ww = w4[t + it * 256];
            int sv[4]   = {ss.x, ss.y, ss.z, ss.w};
            int dv[4]   = {dd.x, dd.y, dd.z, dd.w};
            float wv[4] = {ww.x, ww.y, ww.z, ww.w};
            #pragma unroll
            for (int k = 0; k < 4; ++k) {
                int d = dv[k];
                int b = d >> BUCK_SHIFT;
                int r = atomicAdd(&lcnt[b], 1);
                float wf = wv[k] * scale_tab[sv[k]];
                unsigned lo = (unsigned)sv[k] | ((unsigned)(d & (BUCK_NODES - 1)) << 16);
                unsigned long long rec = (unsigned long long)lo
                                       | ((unsigned long long)__float_as_uint(wf) << 32);
                binned[lbase[b] + r] = rec;
            }
        }
    } else {
        for (int e = base + t; e < NEDGES; e += 256) {
            int d = dst[e];
            int b = d >> BUCK_SHIFT;
            int r = atomicAdd(&lcnt[b], 1);
            int sidx = src[e];
            float wf = wt[e] * scale_tab[sidx];
            unsigned lo = (unsigned)sidx | ((unsigned)(d & (BUCK_NODES - 1)) << 16);
            unsigned long long rec = (unsigned long long)lo
                                   | ((unsigned long long)__float_as_uint(wf) << 32);
            binned[lbase[b] + r] = rec;
        }
    }
}

// ---------------------------------------------------------------------------
// Kernel 4: per-bucket counting sort to per-node CSR. 256 threads (verified);
// bucket range recomputed by inline scan of bcount.
// ---------------------------------------------------------------------------
__global__ __launch_bounds__(256) void sort_buckets(
    const unsigned long long* __restrict__ binned, const int* __restrict__ bcount,
    unsigned long long* __restrict__ csr,
    int* __restrict__ starts, int* __restrict__ counts)
{
    __shared__ int s[256];
    __shared__ int lcnt[BUCK_NODES];
    __shared__ int lcur[BUCK_NODES];
    __shared__ int sh_s0, sh_e0;
    int t = threadIdx.x;
    int b = blockIdx.x;

    // inline scan of bucket counts -> this bucket's [s0, e0)
    int v = (t < NBUCK) ? bcount[t * CPAD] : 0;
    s[t] = v;
    lcnt[t] = 0;
    __syncthreads();
    #pragma unroll
    for (int off = 1; off < 256; off <<= 1) {
        int u = (t >= off) ? s[t - off] : 0;
        __syncthreads();
        s[t] += u;
        __syncthreads();
    }
    if (t == b) { sh_e0 = s[t]; sh_s0 = s[t] - v; }
    __syncthreads();
    int s0 = sh_s0, e0 = sh_e0;
    int node0 = b << BUCK_SHIFT;
    int nn = min(BUCK_NODES, NNODES - node0);

    for (int k = s0 + t; k < e0; k += 256)
        atomicAdd(&lcnt[(int)((binned[k] >> 16) & 0xFF)], 1);
    __syncthreads();

    int v2 = lcnt[t];
    s[t] = v2; __syncthreads();
    #pragma unroll
    for (int off = 1; off < 256; off <<= 1) {
        int u = (t >= off) ? s[t - off] : 0;
        __syncthreads();
        s[t] += u;
        __syncthreads();
    }
    int excl = s[t] - v2;
    lcur[t] = s0 + excl;
    if (t < nn) {
        starts[node0 + t] = s0 + excl;
        counts[node0 + t] = v2;
    }
    __syncthreads();

    for (int k = s0 + t; k < e0; k += 256) {
        unsigned long long r = binned[k];
        int dloc = (int)((r >> 16) & 0xFF);
        int pos  = atomicAdd(&lcur[dloc], 1);
        csr[pos] = r;
    }
}

// ---------------------------------------------------------------------------
// Kernel 5: aggregation. One wave per node, node in SGPR via readfirstlane,
// x8 unroll (8 independent 64B int8-row gathers in flight). Scale pre-folded.
// ---------------------------------------------------------------------------
__global__ __launch_bounds__(256) void agg_nodes(
    const int2* __restrict__ recs, const int* __restrict__ starts,
    const int* __restrict__ counts, const signed char* __restrict__ hq,
    const float* __restrict__ bias, float* __restrict__ out)
{
    int wid  = (blockIdx.x * 256 + threadIdx.x) >> 6;
    int node = __builtin_amdgcn_readfirstlane(wid);
    if (node >= NNODES) return;
    int lane = threadIdx.x & 63;

    float acc = bias[lane];
    int s0  = starts[node];
    int cnt = counts[node];
    int i = s0, e = s0 + cnt;

    for (; i + 7 < e; i += 8) {
        int2 r0 = recs[i + 0];
        int2 r1 = recs[i + 1];
        int2 r2 = recs[i + 2];
        int2 r3 = recs[i + 3];
        int2 r4 = recs[i + 4];
        int2 r5 = recs[i + 5];
        int2 r6 = recs[i + 6];
        int2 r7 = recs[i + 7];
        float v0 = (float)hq[(r0.x & 0xFFFF) * D_OUT + lane];
        float v1 = (float)hq[(r1.x & 0xFFFF) * D_OUT + lane];
        float v2 = (float)hq[(r2.x & 0xFFFF) * D_OUT + lane];
        float v3 = (float)hq[(r3.x & 0xFFFF) * D_OUT + lane];
        float v4 = (float)hq[(r4.x & 0xFFFF) * D_OUT + lane];
        float v5 = (float)hq[(r5.x & 0xFFFF) * D_OUT + lane];
        float v6 = (float)hq[(r6.x & 0xFFFF) * D_OUT + lane];
        float v7 = (float)hq[(r7.x & 0xFFFF) * D_OUT + lane];
        acc += __int_as_float(r0.y) * v0;
        acc += __int_as_float(r1.y) * v1;
        acc += __int_as_float(r2.y) * v2;
        acc += __int_as_float(r3.y) * v3;
        acc += __int_as_float(r4.y) * v4;
        acc += __int_as_float(r5.y) * v5;
        acc += __int_as_float(r6.y) * v6;
        acc += __int_as_float(r7.y) * v7;
    }
    for (; i + 3 < e; i += 4) {
        int2 r0 = recs[i + 0];
        int2 r1 = recs[i + 1];
        int2 r2 = recs[i + 2];
        int2 r3 = recs[i + 3];
        float v0 = (float)hq[(r0.x & 0xFFFF) * D_OUT + lane];
        float v1 = (float)hq[(r1.x & 0xFFFF) * D_OUT + lane];
        float v2 = (float)hq[(r2.x & 0xFFFF) * D_OUT + lane];
        float v3 = (float)hq[(r3.x & 0xFFFF) * D_OUT + lane];
        acc += __int_as_float(r0.y) * v0;
        acc += __int_as_float(r1.y) * v1;
        acc += __int_as_float(r2.y) * v2;
        acc += __int_as_float(r3.y) * v3;
    }
    for (; i < e; ++i) {
        int2 r = recs[i];
        acc += __int_as_float(r.y) * (float)hq[(r.x & 0xFFFF) * D_OUT + lane];
    }
    out[(long long)node * D_OUT + lane] = acc;
}

// ---------------------------------------------------------------------------
// Fallback path (ws too small): bias init + per-edge atomics (int8 h)
// ---------------------------------------------------------------------------
__global__ __launch_bounds__(256) void init_bias(
    float* __restrict__ out, const float* __restrict__ bias, int total)
{
    int i = blockIdx.x * blockDim.x + threadIdx.x;
    if (i < total) out[i] = bias[i & (D_OUT - 1)];
}

__global__ __launch_bounds__(256) void scatter_edges(
    const int* __restrict__ src, const int* __restrict__ dst,
    const float* __restrict__ wt, const signed char* __restrict__ hq,
    const float* __restrict__ scale_tab, float* __restrict__ out)
{
    long long gid = (long long)blockIdx.x * blockDim.x + threadIdx.x;
    int e    = (int)(gid >> 6);
    int lane = threadIdx.x & 63;
    if (e < NEDGES) {
        int   s = src[e];
        int   d = dst[e];
        float w = wt[e] * scale_tab[s];
        float v = w * (float)hq[(long long)s * D_OUT + lane];
        atomicAdd(&out[(long long)d * D_OUT + lane], v);
    }
}

// ---------------------------------------------------------------------------
// Launch: 5 dispatches (was 8) — gemm(+Wconv+zero), hist, bin(+scan),
// sort(+scan), agg.
// ---------------------------------------------------------------------------
extern "C" void kernel_launch(void* const* d_in, const int* in_sizes, int n_in,
                              void* d_out, int out_size, void* d_ws, size_t ws_size,
                              hipStream_t stream)
{
    const float* W     = (const float*)d_in[0];   // [64, 256]
    const float* bias  = (const float*)d_in[1];   // [64]
    const int*   edges = (const int*)  d_in[2];   // [2, E]
    const float* wt    = (const float*)d_in[3];   // [E]
    const float* x     = (const float*)d_in[4];   // [N, 256]
    float*       out   = (float*)d_out;           // [N, 64]

    const int* src = edges;
    const int* dst = edges + NEDGES;

    // workspace carve-up (bytes)
    char* ws = (char*)d_ws;
    const size_t OFF_HQ     = 0;                   // 3,200,000  (int8 h)
    const size_t OFF_SCALE  = 3200000;             // 200,000    (fp32 row scales)
    const size_t OFF_RECS   = 3400000;             // 10,000,000 (CSR recs)
    const size_t OFF_STARTS = 13400000;            // 200,000
    const size_t OFF_COUNTS = 13600000;            // 200,000
    const size_t OFF_BCOUNT = 13800000;            // 12,544
    const size_t OFF_BCUR   = 13812544;            // 12,544 (contiguous after bcount)
    const size_t REQUIRED   = 13825088;

    signed char* hq        = (signed char*)(ws + OFF_HQ);
    float*       scale_tab = (float*)(ws + OFF_SCALE);

    if (ws_size >= REQUIRED) {
        unsigned long long* csr     = (unsigned long long*)(ws + OFF_RECS);
        int*                starts  = (int*)(ws + OFF_STARTS);
        int*                counts  = (int*)(ws + OFF_COUNTS);
        int*                bcount  = (int*)(ws + OFF_BCOUNT);
        int*                bcursor = (int*)(ws + OFF_BCUR);

        // d_out doubles as scratch for bucket-binned recs (10 MB <= 12.8 MB);
        // agg_nodes fully overwrites it afterwards.
        unsigned long long* binned = (unsigned long long*)d_out;

        // 1) gemm: h -> int8 + scales; block 0 zeroes bcount+bcursor
        gemm_h_mfma<<<(NNODES + 63) / 64, 256, 0, stream>>>(
            x, W, hq, scale_tab, bcount, 2 * NBUCK * CPAD, NNODES);

        // 2) coarse histogram
        coarse_hist<<<NB_EDGE, 256, 0, stream>>>(dst, bcount);

        // 3) bin (inline scan, relative cursors, scale folding)
        bin_edges<<<NB_EDGE, 256, 0, stream>>>(src, dst, wt, scale_tab,
                                               bcount, bcursor, binned);

        // 4) per-bucket counting sort -> CSR (inline scan)
        sort_buckets<<<NBUCK, 256, 0, stream>>>(binned, bcount, csr, starts, counts);

        // 5) aggregation
        int nb = (NNODES * 64 + 255) / 256;  // 12500 blocks, 4 nodes/block
        agg_nodes<<<nb, 256, 0, stream>>>((const int2*)csr, starts, counts, hq, bias, out);
    } else {
        gemm_h_mfma<<<(NNODES + 63) / 64, 256, 0, stream>>>(
            x, W, hq, scale_tab, (int*)nullptr, 0, NNODES);
        int total = NNODES * D_OUT;
        init_bias<<<(total + 255) / 256, 256, 0, stream>>>(out, bias, total);
        long long threads = (long long)NEDGES * 64;
        int blocks = (int)((threads + 255) / 256);
        scatter_edges<<<blocks, 256, 0, stream>>>(src, dst, wt, hq, scale_tab, out);
    }
}